// Round 7
// baseline (148.840 us; speedup 1.0000x reference)
//
#include <hip/hip_runtime.h>

#define N2 8192
#define NHALF 4096
#define DDIM 128
#define NCHUNK 16
#define CPC (N2/NCHUNK)   // 512 cols per chunk
#define NT (CPC/64)       // 8 tiles of 64 cols
#define RPB 256           // rows per workgroup (4 waves x 64 rows)
#define LN2F 0.69314718055994530942f
// SCALEF = sqrt(log2(e)/T) with T=0.5 -> sqrt(2.8853900817779268)
#define SCALEF 1.6986436f

typedef __attribute__((ext_vector_type(8))) short bf8_t;   // 8 bf16 = 4 VGPR
typedef __attribute__((ext_vector_type(4))) float f4_t;    // MFMA C/D frag

__device__ __forceinline__ float fexp2(float x) { return __builtin_amdgcn_exp2f(x); }
__device__ __forceinline__ float flog2(float x) { return __builtin_amdgcn_logf(x); }

__device__ __forceinline__ unsigned short f2bf(float f) {
  unsigned int x = __float_as_uint(f);
  x += 0x7fffu + ((x >> 16) & 1u);   // RNE (no NaN inputs here)
  return (unsigned short)(x >> 16);
}
__device__ __forceinline__ float bf2f(unsigned short h) {
  return __uint_as_float(((unsigned int)h) << 16);
}

// ---------------------------------------------------------------------------
// Kernel 1: normalize rows, scale by sqrt(log2e/T), store bf16 u[8192][128];
// also store dhat[i] = sum_k u_bf16[i][k]^2 (diag logit, for correction).
// ---------------------------------------------------------------------------
__global__ __launch_bounds__(256) void knorm(const float* __restrict__ zi,
                                             const float* __restrict__ zj,
                                             unsigned short* __restrict__ u,
                                             float* __restrict__ dhat) {
  const int lane = threadIdx.x & 63;
  const int row = blockIdx.x * 4 + (threadIdx.x >> 6);
  const float* src = (row < NHALF) ? (zi + (size_t)row * DDIM)
                                   : (zj + (size_t)(row - NHALF) * DDIM);
  float2 x = *(const float2*)(src + lane * 2);
  float ss = x.x * x.x + x.y * x.y;
#pragma unroll
  for (int m = 32; m; m >>= 1) ss += __shfl_xor(ss, m);
  float scale = SCALEF / fmaxf(sqrtf(ss), 1e-8f);  // eps clamp as in reference
  unsigned short b0 = f2bf(x.x * scale);
  unsigned short b1 = f2bf(x.y * scale);
  *(unsigned int*)(u + (size_t)row * DDIM + lane * 2) =
      (unsigned int)b0 | ((unsigned int)b1 << 16);
  float f0 = bf2f(b0), f1 = bf2f(b1);
  float dd = f0 * f0 + f1 * f1;
#pragma unroll
  for (int m = 32; m; m >>= 1) dd += __shfl_xor(dd, m);
  if (lane == 0) dhat[row] = dd;
}

// ---------------------------------------------------------------------------
// Kernel 2: fused sim GEMM + per-row sum of exp2 (logits bounded, no max).
// r6 post-mortem: global_load_lds with a 16-line per-lane transpose gather
// generated ~170MB phantom HBM write traffic -> HBM-bound. This round: NO
// DMA. Reg-staged LDS (T14): plain contiguous dwordx4 loads -> pinned VGPRs
// -> ds_write_b128 into fragment-major swizzled layout.
//   LDS 16B-unit for (col,d):  unit=(g*4+kc)*64 + ((e*16+lr)^(kc*4))
//     where g=col>>4, lr=col&15, kc=d>>2, e=d&3.
//   COMP read (g,kc), lane l:  unit=(g*4+kc)*64 + (l^(kc*4))
//     -> delivers col=g*16+(l&15), dims kc*32+(l>>4)*8 (validated operand map).
//   Conflicts: read bijective (none), write 2-way (free, m136).
// One raw s_barrier per tile, lgkmcnt(0) only (loads for tile t+2 stay in
// flight across the barrier and hide under COMP's 64 MFMA + 64 exp2).
// grid = 32 row-blocks x 16 chunks = 512 WGs; WG = 256 rows x 512 cols.
// ---------------------------------------------------------------------------
__global__ __launch_bounds__(256, 3) void ksim(const unsigned short* __restrict__ u,
                                               float* __restrict__ Lp) {
  __shared__ short Bl[2][8192];  // 2 x 16 KB
  const int tid = threadIdx.x;
  const int lane = tid & 63;
  const int w = tid >> 6;
  const int rb = blockIdx.x >> 4;        // / NCHUNK
  const int chunk = blockIdx.x & (NCHUNK - 1);
  const int lr = lane & 15, lq = lane >> 4;
  const int rowbase = rb * RPB + w * 64;

  // A fragments: 64 rows per wave, pinned (r5: pin verified via VGPR count)
  bf8_t a[4][4];
#pragma unroll
  for (int s = 0; s < 4; s++)
#pragma unroll
    for (int kc = 0; kc < 4; kc++)
      a[s][kc] = *(const bf8_t*)(u + (size_t)(rowbase + s * 16 + lr) * DDIM +
                                 kc * 32 + lq * 8);
#pragma unroll
  for (int s = 0; s < 4; s++)
#pragma unroll
    for (int kc = 0; kc < 4; kc++)
      asm volatile("" : "+v"(a[s][kc]));

  f4_t L[4];
#pragma unroll
  for (int s = 0; s < 4; s++) L[s] = (f4_t){0.f, 0.f, 0.f, 0.f};

  // Staging geometry (per thread, tile-independent parts)
  const int s_col = tid >> 4;                 // col within 16-col group, 0..15
  const int s_d = tid & 15;                   // 16B dim-unit, 0..15
  const int s_kc = s_d >> 2, s_e = s_d & 3;
  const int s_idxlow = ((s_e * 16 + s_col) ^ (s_kc * 4));
  short* const wp0 = &Bl[0][((size_t)(s_kc * 64 + s_idxlow)) * 8];
  short* const wp1 = &Bl[1][((size_t)(s_kc * 64 + s_idxlow)) * 8];

  bf8_t s0, s1, s2, s3;
  auto SLOAD = [&](int t) {
    const unsigned short* sb =
        u + ((size_t)(chunk * CPC + t * 64 + s_col)) * DDIM + s_d * 8;
    s0 = *(const bf8_t*)(sb);
    s1 = *(const bf8_t*)(sb + 16 * DDIM);
    s2 = *(const bf8_t*)(sb + 32 * DDIM);
    s3 = *(const bf8_t*)(sb + 48 * DDIM);
    asm volatile("" : "+v"(s0), "+v"(s1), "+v"(s2), "+v"(s3));
  };
  auto SWRITE = [&](int bufi) {
    short* wp = bufi ? wp1 : wp0;
    *(bf8_t*)(wp) = s0;                 // it=0
    *(bf8_t*)(wp + 2048) = s1;          // it=1: +4*64 units = +2048 shorts
    *(bf8_t*)(wp + 4096) = s2;          // it=2
    *(bf8_t*)(wp + 6144) = s3;          // it=3
  };
  auto COMPT = [&](int bufi) {
#pragma unroll
    for (int g = 0; g < 4; g++) {
      f4_t acc[4];
#pragma unroll
      for (int s = 0; s < 4; s++) acc[s] = (f4_t){0.f, 0.f, 0.f, 0.f};
#pragma unroll
      for (int kc = 0; kc < 4; kc++) {
        bf8_t bv = *(const bf8_t*)&Bl[bufi][((size_t)((g * 4 + kc) * 64 +
                                                      (lane ^ (kc * 4)))) * 8];
#pragma unroll
        for (int s = 0; s < 4; s++)
          acc[s] = __builtin_amdgcn_mfma_f32_16x16x32_bf16(a[s][kc], bv, acc[s], 0, 0, 0);
      }
#pragma unroll
      for (int s = 0; s < 4; s++)
#pragma unroll
        for (int r = 0; r < 4; r++) L[s][r] += fexp2(acc[s][r]);
    }
  };
  auto KBAR = [&]() {
    asm volatile("s_waitcnt lgkmcnt(0)" ::: "memory");
    __builtin_amdgcn_sched_barrier(0);
    __builtin_amdgcn_s_barrier();
    __builtin_amdgcn_sched_barrier(0);
  };

  // prologue
  SLOAD(0);
  SWRITE(0);      // compiler auto-waits vmcnt for the s0..s3 deps
  SLOAD(1);
  KBAR();
  // steady state: 1 barrier per tile; loads for t+2 in flight across it
#pragma unroll
  for (int t = 0; t < NT - 2; t++) {
    COMPT(t & 1);
    SWRITE((t + 1) & 1);
    SLOAD(t + 2);
    KBAR();
  }
  COMPT((NT - 2) & 1);   // tile 6 (buf0)
  SWRITE((NT - 1) & 1);  // tile 7 -> buf1
  KBAR();
  COMPT((NT - 1) & 1);   // tile 7

  // reduce across the 16 column-lanes (lanes sharing lq hold the same rows)
#pragma unroll
  for (int s = 0; s < 4; s++)
#pragma unroll
    for (int r = 0; r < 4; r++) {
      float v = L[s][r];
      v += __shfl_xor(v, 1); v += __shfl_xor(v, 2);
      v += __shfl_xor(v, 4); v += __shfl_xor(v, 8);
      if (lr == 0)
        Lp[(size_t)chunk * N2 + rowbase + s * 16 + lq * 4 + r] = v;
    }
}

// ---------------------------------------------------------------------------
// Kernel 3: per-row loss. L_i = sum_chunks - exp2(dhat_i) (removes diagonal);
// target logit from direct bf16 dot; loss_i = ln2*(log2(L_i) - target).
// ---------------------------------------------------------------------------
__global__ __launch_bounds__(256) void krow(const unsigned short* __restrict__ u,
                                            const float* __restrict__ dhat,
                                            const float* __restrict__ Lp,
                                            float* __restrict__ bsum) {
  const int i = blockIdx.x * 256 + threadIdx.x;
  float L = 0.f;
#pragma unroll
  for (int c = 0; c < NCHUNK; c++) L += Lp[(size_t)c * N2 + i];
  L -= fexp2(dhat[i]);   // remove self-similarity term (== diag set to -inf)

  const int j = (i + NHALF) & (N2 - 1);  // positive-pair label
  const unsigned int* ui = (const unsigned int*)(u + (size_t)i * DDIM);
  const unsigned int* uj = (const unsigned int*)(u + (size_t)j * DDIM);
  float dot = 0.f;
#pragma unroll
  for (int k = 0; k < DDIM / 2; k++) {
    unsigned int av = ui[k], bv = uj[k];
    dot += __uint_as_float(av << 16) * __uint_as_float(bv << 16) +
           __uint_as_float(av & 0xffff0000u) * __uint_as_float(bv & 0xffff0000u);
  }
  float loss = LN2F * (flog2(L) - dot);

#pragma unroll
  for (int m = 32; m; m >>= 1) loss += __shfl_xor(loss, m);
  __shared__ float sred[4];
  if ((threadIdx.x & 63) == 0) sred[threadIdx.x >> 6] = loss;
  __syncthreads();
  if (threadIdx.x == 0) bsum[blockIdx.x] = sred[0] + sred[1] + sred[2] + sred[3];
}

// ---------------------------------------------------------------------------
// Kernel 4: final mean over the 32 block partials.
// ---------------------------------------------------------------------------
__global__ void kfinal(const float* __restrict__ bsum, float* __restrict__ out) {
  float v = (threadIdx.x < N2 / 256) ? bsum[threadIdx.x] : 0.f;
#pragma unroll
  for (int m = 32; m; m >>= 1) v += __shfl_xor(v, m);
  if (threadIdx.x == 0) out[0] = v * (1.0f / N2);
}

// ---------------------------------------------------------------------------
// ws layout: u bf16 [8192][128] (2 MB) | dhat f32[8192] (32 KB) |
//            Lp f32[NCHUNK][8192] (512 KB) | bsum f32[32]  -> ~2.6 MB total
// ---------------------------------------------------------------------------
extern "C" void kernel_launch(void* const* d_in, const int* in_sizes, int n_in,
                              void* d_out, int out_size, void* d_ws, size_t ws_size,
                              hipStream_t stream) {
  const float* zi = (const float*)d_in[0];
  const float* zj = (const float*)d_in[1];
  char* ws = (char*)d_ws;
  unsigned short* u = (unsigned short*)ws;
  float* dhat = (float*)(ws + (size_t)N2 * DDIM * 2);
  float* Lp = (float*)(ws + (size_t)N2 * DDIM * 2 + (size_t)N2 * 4);
  float* bsum = (float*)(ws + (size_t)N2 * DDIM * 2 + (size_t)N2 * 4 +
                         (size_t)NCHUNK * N2 * 4);
  float* out = (float*)d_out;

  hipLaunchKernelGGL(knorm, dim3(N2 / 4), dim3(256), 0, stream, zi, zj, u, dhat);
  hipLaunchKernelGGL(ksim, dim3((N2 / RPB) * NCHUNK), dim3(256), 0, stream, u, Lp);
  hipLaunchKernelGGL(krow, dim3(N2 / 256), dim3(256), 0, stream, u, dhat, Lp, bsum);
  hipLaunchKernelGGL(kfinal, dim3(1), dim3(64), 0, stream, bsum, out);
}

// Round 8
// 140.919 us; speedup vs baseline: 1.0562x; 1.0562x over previous
//
#include <hip/hip_runtime.h>

#define N2 8192
#define NHALF 4096
#define DDIM 128
#define NCHUNK 32
#define CPC (N2/NCHUNK)   // 256 cols per chunk
#define NT (CPC/64)       // 4 tiles of 64 cols
#define RPB 256           // rows per workgroup (4 waves x 64 rows)
#define LN2F 0.69314718055994530942f
// SCALEF = sqrt(log2(e)/T) with T=0.5 -> sqrt(2.8853900817779268)
#define SCALEF 1.6986436f

typedef __attribute__((ext_vector_type(8))) short bf8_t;   // 8 bf16 = 4 VGPR
typedef __attribute__((ext_vector_type(4))) float f4_t;    // MFMA C/D frag

__device__ __forceinline__ float fexp2(float x) { return __builtin_amdgcn_exp2f(x); }
__device__ __forceinline__ float flog2(float x) { return __builtin_amdgcn_logf(x); }

__device__ __forceinline__ unsigned short f2bf(float f) {
  unsigned int x = __float_as_uint(f);
  x += 0x7fffu + ((x >> 16) & 1u);   // RNE (no NaN inputs here)
  return (unsigned short)(x >> 16);
}
__device__ __forceinline__ float bf2f(unsigned short h) {
  return __uint_as_float(((unsigned int)h) << 16);
}

// ---------------------------------------------------------------------------
// Kernel 1: normalize rows, scale by sqrt(log2e/T), store bf16 u[8192][128];
// also store dhat[i] = sum_k u_bf16[i][k]^2 (diag logit, for correction).
// ---------------------------------------------------------------------------
__global__ __launch_bounds__(256) void knorm(const float* __restrict__ zi,
                                             const float* __restrict__ zj,
                                             unsigned short* __restrict__ u,
                                             float* __restrict__ dhat) {
  const int lane = threadIdx.x & 63;
  const int row = blockIdx.x * 4 + (threadIdx.x >> 6);
  const float* src = (row < NHALF) ? (zi + (size_t)row * DDIM)
                                   : (zj + (size_t)(row - NHALF) * DDIM);
  float2 x = *(const float2*)(src + lane * 2);
  float ss = x.x * x.x + x.y * x.y;
#pragma unroll
  for (int m = 32; m; m >>= 1) ss += __shfl_xor(ss, m);
  float scale = SCALEF / fmaxf(sqrtf(ss), 1e-8f);  // eps clamp as in reference
  unsigned short b0 = f2bf(x.x * scale);
  unsigned short b1 = f2bf(x.y * scale);
  *(unsigned int*)(u + (size_t)row * DDIM + lane * 2) =
      (unsigned int)b0 | ((unsigned int)b1 << 16);
  float f0 = bf2f(b0), f1 = bf2f(b1);
  float dd = f0 * f0 + f1 * f1;
#pragma unroll
  for (int m = 32; m; m >>= 1) dd += __shfl_xor(dd, m);
  if (lane == 0) dhat[row] = dd;
}

// ---------------------------------------------------------------------------
// Kernel 2: fused sim GEMM + per-row sum of exp2 (logits bounded, no max).
// r7 post-mortem: scattered VMEM (strided reg-staging + frag gathers) blew up
// the memory system (FETCH 180MB) and LDS writes were 8-way conflicted.
// This round = proven m97/m201 mechanics:
//  * B staged by global_load_lds, source LANE-CONTIGUOUS (1KB/instr, 8 full
//    128B lines). Layout permutation applied on the GLOBAL side per-lane
//    within the 1KB region (m173 pre-swizzle; LDS dest stays linear).
//  * Unit-level involution f(U)=U^(col&7) (16B units): LDS_unit[U] holds
//    B_unit[f(U)]. Fragment read for (g,kc), lane l (lr=l&15, lq=l>>4):
//    U = (g*16+lr)*16 + ((kc*4+lq)^(lr&7))  -> ~2-way banks (free, m136).
//  * Counted s_waitcnt vmcnt(4) + raw s_barrier, double-buffered, never
//    vmcnt(0) in the steady loop (r6 sync, correctness-proven).
// A fragments loaded once and pinned (VGPR count verifies). grid = 32
// row-blocks x 32 chunks = 1024 WGs (4/CU); WG = 256 rows x 256 cols.
// ---------------------------------------------------------------------------
__global__ __launch_bounds__(256, 4) void ksim(const unsigned short* __restrict__ u,
                                               float* __restrict__ Lp) {
  __shared__ short Bl[2][8192];  // 2 x 16 KB (64 cols x 256B, 16B-unit granular)
  const int tid = threadIdx.x;
  const int lane = tid & 63;
  const int w = tid >> 6;
  const int rb = blockIdx.x >> 5;        // / NCHUNK
  const int chunk = blockIdx.x & (NCHUNK - 1);
  const int lr = lane & 15, lq = lane >> 4;
  const int rowbase = rb * RPB + w * 64;

  // A fragments: 64 rows per wave, loaded once, pinned.
  bf8_t a[4][4];
#pragma unroll
  for (int s = 0; s < 4; s++)
#pragma unroll
    for (int kc = 0; kc < 4; kc++)
      a[s][kc] = *(const bf8_t*)(u + (size_t)(rowbase + s * 16 + lr) * DDIM +
                                 kc * 32 + lq * 8);
#pragma unroll
  for (int s = 0; s < 4; s++)
#pragma unroll
    for (int kc = 0; kc < 4; kc++)
      asm volatile("" : "+v"(a[s][kc]));

  f4_t L[4];
#pragma unroll
  for (int s = 0; s < 4; s++) L[s] = (f4_t){0.f, 0.f, 0.f, 0.f};

  // Staging: instr (w,i) covers LDS units [(w*4+i)*64, +64): 4 cols, linear.
  // Per-lane global src = element that belongs at unit U=(w*4+i)*64+l under
  // the involution: col = (w*4+i)*4 + lq;  du_src = (l&15) ^ (col&7)
  // where col&7 = (4*(i&1)+lq). Source spans the SAME contiguous 1KB region.
  auto STAGE = [&](int t, int bufi) {
    const int colbase = chunk * CPC + t * 64;
#pragma unroll
    for (int i = 0; i < 4; i++) {
      const int gi = w * 4 + i;                       // wave-uniform
      const int col = colbase + gi * 4 + lq;          // per-lane (lq part)
      const int du = lr ^ (4 * (i & 1) + lq);         // swizzled 16B-unit
      const unsigned short* src = u + (size_t)col * DDIM + du * 8;
      short* dst = &Bl[bufi][(size_t)gi * 512];       // wave-uniform, linear
      __builtin_amdgcn_global_load_lds(
          (const __attribute__((address_space(1))) unsigned int*)src,
          (__attribute__((address_space(3))) unsigned int*)dst, 16, 0, 0);
    }
  };

  auto COMPT = [&](int bufi) {
#pragma unroll
    for (int g = 0; g < 4; g++) {
      f4_t acc[4];
#pragma unroll
      for (int s = 0; s < 4; s++) acc[s] = (f4_t){0.f, 0.f, 0.f, 0.f};
#pragma unroll
      for (int kc = 0; kc < 4; kc++) {
        const int U = (g * 16 + lr) * 16 + ((kc * 4 + lq) ^ (lr & 7));
        bf8_t bv = *(const bf8_t*)&Bl[bufi][(size_t)U * 8];
#pragma unroll
        for (int s = 0; s < 4; s++)
          acc[s] = __builtin_amdgcn_mfma_f32_16x16x32_bf16(a[s][kc], bv, acc[s], 0, 0, 0);
      }
#pragma unroll
      for (int s = 0; s < 4; s++)
#pragma unroll
        for (int r = 0; r < 4; r++) L[s][r] += fexp2(acc[s][r]);
    }
  };

  // prologue: two tiles in flight
  STAGE(0, 0);
  STAGE(1, 1);
#pragma unroll
  for (int t = 0; t < NT - 2; t++) {
    asm volatile("s_waitcnt vmcnt(4)" ::: "memory");  // my tile-t DMAs done
    __builtin_amdgcn_sched_barrier(0);
    __builtin_amdgcn_s_barrier();                     // everyone's tile-t done
    __builtin_amdgcn_sched_barrier(0);
    COMPT(t & 1);
    __builtin_amdgcn_s_barrier();                     // all done reading buf
    __builtin_amdgcn_sched_barrier(0);
    STAGE(t + 2, t & 1);
  }
  asm volatile("s_waitcnt vmcnt(4)" ::: "memory");
  __builtin_amdgcn_sched_barrier(0);
  __builtin_amdgcn_s_barrier();
  __builtin_amdgcn_sched_barrier(0);
  COMPT(NT & 1);         // tile NT-2
  asm volatile("s_waitcnt vmcnt(0)" ::: "memory");
  __builtin_amdgcn_sched_barrier(0);
  __builtin_amdgcn_s_barrier();
  __builtin_amdgcn_sched_barrier(0);
  COMPT((NT - 1) & 1);   // tile NT-1

  // reduce across the 16 column-lanes (lanes sharing lq hold the same rows)
#pragma unroll
  for (int s = 0; s < 4; s++)
#pragma unroll
    for (int r = 0; r < 4; r++) {
      float v = L[s][r];
      v += __shfl_xor(v, 1); v += __shfl_xor(v, 2);
      v += __shfl_xor(v, 4); v += __shfl_xor(v, 8);
      if (lr == 0)
        Lp[(size_t)chunk * N2 + rowbase + s * 16 + lq * 4 + r] = v;
    }
}

// ---------------------------------------------------------------------------
// Kernel 3: per-row loss. L_i = sum_chunks - exp2(dhat_i) (removes diagonal);
// target logit from direct bf16 dot; loss_i = ln2*(log2(L_i) - target).
// ---------------------------------------------------------------------------
__global__ __launch_bounds__(256) void krow(const unsigned short* __restrict__ u,
                                            const float* __restrict__ dhat,
                                            const float* __restrict__ Lp,
                                            float* __restrict__ bsum) {
  const int i = blockIdx.x * 256 + threadIdx.x;
  float L = 0.f;
#pragma unroll
  for (int c = 0; c < NCHUNK; c++) L += Lp[(size_t)c * N2 + i];
  L -= fexp2(dhat[i]);   // remove self-similarity term (== diag set to -inf)

  const int j = (i + NHALF) & (N2 - 1);  // positive-pair label
  const unsigned int* ui = (const unsigned int*)(u + (size_t)i * DDIM);
  const unsigned int* uj = (const unsigned int*)(u + (size_t)j * DDIM);
  float dot = 0.f;
#pragma unroll
  for (int k = 0; k < DDIM / 2; k++) {
    unsigned int av = ui[k], bv = uj[k];
    dot += __uint_as_float(av << 16) * __uint_as_float(bv << 16) +
           __uint_as_float(av & 0xffff0000u) * __uint_as_float(bv & 0xffff0000u);
  }
  float loss = LN2F * (flog2(L) - dot);

#pragma unroll
  for (int m = 32; m; m >>= 1) loss += __shfl_xor(loss, m);
  __shared__ float sred[4];
  if ((threadIdx.x & 63) == 0) sred[threadIdx.x >> 6] = loss;
  __syncthreads();
  if (threadIdx.x == 0) bsum[blockIdx.x] = sred[0] + sred[1] + sred[2] + sred[3];
}

// ---------------------------------------------------------------------------
// Kernel 4: final mean over the 32 block partials.
// ---------------------------------------------------------------------------
__global__ void kfinal(const float* __restrict__ bsum, float* __restrict__ out) {
  float v = (threadIdx.x < N2 / 256) ? bsum[threadIdx.x] : 0.f;
#pragma unroll
  for (int m = 32; m; m >>= 1) v += __shfl_xor(v, m);
  if (threadIdx.x == 0) out[0] = v * (1.0f / N2);
}

// ---------------------------------------------------------------------------
// ws layout: u bf16 [8192][128] (2 MB) | dhat f32[8192] (32 KB) |
//            Lp f32[NCHUNK][8192] (1 MB) | bsum f32[32]  -> ~3.03 MB total
// ---------------------------------------------------------------------------
extern "C" void kernel_launch(void* const* d_in, const int* in_sizes, int n_in,
                              void* d_out, int out_size, void* d_ws, size_t ws_size,
                              hipStream_t stream) {
  const float* zi = (const float*)d_in[0];
  const float* zj = (const float*)d_in[1];
  char* ws = (char*)d_ws;
  unsigned short* u = (unsigned short*)ws;
  float* dhat = (float*)(ws + (size_t)N2 * DDIM * 2);
  float* Lp = (float*)(ws + (size_t)N2 * DDIM * 2 + (size_t)N2 * 4);
  float* bsum = (float*)(ws + (size_t)N2 * DDIM * 2 + (size_t)N2 * 4 +
                         (size_t)NCHUNK * N2 * 4);
  float* out = (float*)d_out;

  hipLaunchKernelGGL(knorm, dim3(N2 / 4), dim3(256), 0, stream, zi, zj, u, dhat);
  hipLaunchKernelGGL(ksim, dim3((N2 / RPB) * NCHUNK), dim3(256), 0, stream, u, Lp);
  hipLaunchKernelGGL(krow, dim3(N2 / 256), dim3(256), 0, stream, u, dhat, Lp, bsum);
  hipLaunchKernelGGL(kfinal, dim3(1), dim3(64), 0, stream, bsum, out);
}

// Round 9
// 114.443 us; speedup vs baseline: 1.3006x; 1.2314x over previous
//
#include <hip/hip_runtime.h>

#define N2 8192
#define NHALF 4096
#define DDIM 128
#define NCHUNK 32
#define CPC (N2/NCHUNK)   // 256 cols per chunk -> 16 tiles of 16 cols
#define RPB 128           // rows per workgroup (4 waves x 32 rows)
#define LN2F 0.69314718055994530942f
// SCALEF = sqrt(log2(e)/T) with T=0.5 -> sqrt(2.8853900817779268)
#define SCALEF 1.6986436f

typedef __attribute__((ext_vector_type(8))) short bf8_t;   // 8 bf16 = 4 VGPR
typedef __attribute__((ext_vector_type(4))) float f4_t;    // MFMA C/D frag

__device__ __forceinline__ float fexp2(float x) { return __builtin_amdgcn_exp2f(x); }
__device__ __forceinline__ float flog2(float x) { return __builtin_amdgcn_logf(x); }

__device__ __forceinline__ unsigned short f2bf(float f) {
  unsigned int x = __float_as_uint(f);
  x += 0x7fffu + ((x >> 16) & 1u);   // RNE (no NaN inputs here)
  return (unsigned short)(x >> 16);
}
__device__ __forceinline__ float bf2f(unsigned short h) {
  return __uint_as_float(((unsigned int)h) << 16);
}

// ---------------------------------------------------------------------------
// Kernel 1: normalize rows, scale by sqrt(log2e/T), store bf16 u[8192][128];
// also store dhat[i] = sum_k u_bf16[i][k]^2 (diag logit, for correction).
// ---------------------------------------------------------------------------
__global__ __launch_bounds__(256) void knorm(const float* __restrict__ zi,
                                             const float* __restrict__ zj,
                                             unsigned short* __restrict__ u,
                                             float* __restrict__ dhat) {
  const int lane = threadIdx.x & 63;
  const int row = blockIdx.x * 4 + (threadIdx.x >> 6);
  const float* src = (row < NHALF) ? (zi + (size_t)row * DDIM)
                                   : (zj + (size_t)(row - NHALF) * DDIM);
  float2 x = *(const float2*)(src + lane * 2);
  float ss = x.x * x.x + x.y * x.y;
#pragma unroll
  for (int m = 32; m; m >>= 1) ss += __shfl_xor(ss, m);
  float scale = SCALEF / fmaxf(sqrtf(ss), 1e-8f);  // eps clamp as in reference
  unsigned short b0 = f2bf(x.x * scale);
  unsigned short b1 = f2bf(x.y * scale);
  *(unsigned int*)(u + (size_t)row * DDIM + lane * 2) =
      (unsigned int)b0 | ((unsigned int)b1 << 16);
  float f0 = bf2f(b0), f1 = bf2f(b1);
  float dd = f0 * f0 + f1 * f1;
#pragma unroll
  for (int m = 32; m; m >>= 1) dd += __shfl_xor(dd, m);
  if (lane == 0) dhat[row] = dd;
}

// ---------------------------------------------------------------------------
// Kernel 2: fused sim GEMM + per-row sum of exp2 (logits bounded, no max).
// r4-r8 post-mortem: every large-register design was rematerialized (r4) or
// scratch-spilled (r7/r8: WRITE 218MB = scratch). The ONLY configs with sane
// memory behavior were the simple <=64-VGPR loops (r3: VGPR=56, FETCH 8MB),
// which were purely latency-bound at 2 WG/CU.
// This round: identical structure to r3 (a[2][4]+L+b = 56 VGPR, everything
// resident), but occupancy 4x: NCHUNK=32 -> grid 2048 WGs = 8 WG/CU, and
// __launch_bounds__(256,8) -> 8 waves/SIMD at <=64 VGPR. Latency is hidden
// by TLP, not ILP; 4 lockstep waves/WG re-reading the same B-frags hit L1.
// D-frag layout (validated r3+): col = lane&15, row = (lane>>4)*4 + reg.
// ---------------------------------------------------------------------------
__global__ __launch_bounds__(256, 8) void ksim(const unsigned short* __restrict__ u,
                                               float* __restrict__ Lp) {
  const int lane = threadIdx.x & 63;
  const int w = threadIdx.x >> 6;
  const int rb = blockIdx.x >> 5;        // / NCHUNK
  const int chunk = blockIdx.x & (NCHUNK - 1);
  const int lr = lane & 15, lq = lane >> 4;
  const int rowbase = rb * RPB + w * 32;

  bf8_t a[2][4];
#pragma unroll
  for (int s = 0; s < 2; s++)
#pragma unroll
    for (int kc = 0; kc < 4; kc++)
      a[s][kc] = *(const bf8_t*)(u + (size_t)(rowbase + s * 16 + lr) * DDIM +
                                 kc * 32 + lq * 8);

  f4_t L0 = {0.f, 0.f, 0.f, 0.f}, L1 = {0.f, 0.f, 0.f, 0.f};
  const unsigned short* ub = u + (size_t)(chunk * CPC + lr) * DDIM + lq * 8;

  for (int t = 0; t < CPC / 16; t++) {
    bf8_t b[4];
#pragma unroll
    for (int kc = 0; kc < 4; kc++)
      b[kc] = *(const bf8_t*)(ub + (size_t)t * 16 * DDIM + kc * 32);
    f4_t acc0 = {0.f, 0.f, 0.f, 0.f}, acc1 = {0.f, 0.f, 0.f, 0.f};
#pragma unroll
    for (int kc = 0; kc < 4; kc++) {
      acc0 = __builtin_amdgcn_mfma_f32_16x16x32_bf16(a[0][kc], b[kc], acc0, 0, 0, 0);
      acc1 = __builtin_amdgcn_mfma_f32_16x16x32_bf16(a[1][kc], b[kc], acc1, 0, 0, 0);
    }
#pragma unroll
    for (int r = 0; r < 4; r++) {
      L0[r] += fexp2(acc0[r]);
      L1[r] += fexp2(acc1[r]);
    }
  }

  // reduce across the 16 column-lanes (lanes sharing lq hold the same rows)
#pragma unroll
  for (int r = 0; r < 4; r++) {
    float v0 = L0[r], v1 = L1[r];
    v0 += __shfl_xor(v0, 1); v0 += __shfl_xor(v0, 2);
    v0 += __shfl_xor(v0, 4); v0 += __shfl_xor(v0, 8);
    v1 += __shfl_xor(v1, 1); v1 += __shfl_xor(v1, 2);
    v1 += __shfl_xor(v1, 4); v1 += __shfl_xor(v1, 8);
    if (lr == 0) {
      int rrow = rowbase + lq * 4 + r;
      Lp[(size_t)chunk * N2 + rrow] = v0;        // A-set 0 rows
      Lp[(size_t)chunk * N2 + rrow + 16] = v1;   // A-set 1 rows
    }
  }
}

// ---------------------------------------------------------------------------
// Kernel 3: per-row loss. L_i = sum_chunks - exp2(dhat_i) (removes diagonal);
// target logit from direct bf16 dot; loss_i = ln2*(log2(L_i) - target).
// ---------------------------------------------------------------------------
__global__ __launch_bounds__(256) void krow(const unsigned short* __restrict__ u,
                                            const float* __restrict__ dhat,
                                            const float* __restrict__ Lp,
                                            float* __restrict__ bsum) {
  const int i = blockIdx.x * 256 + threadIdx.x;
  float L = 0.f;
#pragma unroll
  for (int c = 0; c < NCHUNK; c++) L += Lp[(size_t)c * N2 + i];
  L -= fexp2(dhat[i]);   // remove self-similarity term (== diag set to -inf)

  const int j = (i + NHALF) & (N2 - 1);  // positive-pair label
  const unsigned int* ui = (const unsigned int*)(u + (size_t)i * DDIM);
  const unsigned int* uj = (const unsigned int*)(u + (size_t)j * DDIM);
  float dot = 0.f;
#pragma unroll
  for (int k = 0; k < DDIM / 2; k++) {
    unsigned int av = ui[k], bv = uj[k];
    dot += __uint_as_float(av << 16) * __uint_as_float(bv << 16) +
           __uint_as_float(av & 0xffff0000u) * __uint_as_float(bv & 0xffff0000u);
  }
  float loss = LN2F * (flog2(L) - dot);

#pragma unroll
  for (int m = 32; m; m >>= 1) loss += __shfl_xor(loss, m);
  __shared__ float sred[4];
  if ((threadIdx.x & 63) == 0) sred[threadIdx.x >> 6] = loss;
  __syncthreads();
  if (threadIdx.x == 0) bsum[blockIdx.x] = sred[0] + sred[1] + sred[2] + sred[3];
}

// ---------------------------------------------------------------------------
// Kernel 4: final mean over the 32 block partials.
// ---------------------------------------------------------------------------
__global__ void kfinal(const float* __restrict__ bsum, float* __restrict__ out) {
  float v = (threadIdx.x < N2 / 256) ? bsum[threadIdx.x] : 0.f;
#pragma unroll
  for (int m = 32; m; m >>= 1) v += __shfl_xor(v, m);
  if (threadIdx.x == 0) out[0] = v * (1.0f / N2);
}

// ---------------------------------------------------------------------------
// ws layout: u bf16 [8192][128] (2 MB) | dhat f32[8192] (32 KB) |
//            Lp f32[NCHUNK][8192] (1 MB) | bsum f32[32]  -> ~3.03 MB total
// ---------------------------------------------------------------------------
extern "C" void kernel_launch(void* const* d_in, const int* in_sizes, int n_in,
                              void* d_out, int out_size, void* d_ws, size_t ws_size,
                              hipStream_t stream) {
  const float* zi = (const float*)d_in[0];
  const float* zj = (const float*)d_in[1];
  char* ws = (char*)d_ws;
  unsigned short* u = (unsigned short*)ws;
  float* dhat = (float*)(ws + (size_t)N2 * DDIM * 2);
  float* Lp = (float*)(ws + (size_t)N2 * DDIM * 2 + (size_t)N2 * 4);
  float* bsum = (float*)(ws + (size_t)N2 * DDIM * 2 + (size_t)N2 * 4 +
                         (size_t)NCHUNK * N2 * 4);
  float* out = (float*)d_out;

  hipLaunchKernelGGL(knorm, dim3(N2 / 4), dim3(256), 0, stream, zi, zj, u, dhat);
  hipLaunchKernelGGL(ksim, dim3((N2 / RPB) * NCHUNK), dim3(256), 0, stream, u, Lp);
  hipLaunchKernelGGL(krow, dim3(N2 / 256), dim3(256), 0, stream, u, dhat, Lp, bsum);
  hipLaunchKernelGGL(kfinal, dim3(1), dim3(64), 0, stream, bsum, out);
}

// Round 10
// 83.501 us; speedup vs baseline: 1.7825x; 1.3706x over previous
//
#include <hip/hip_runtime.h>

#define N2 8192
#define NHALF 4096
#define DDIM 128
#define NCHUNK 32
#define CPC (N2/NCHUNK)   // 256 cols per chunk -> 16 tiles of 16 cols
#define RPB 128           // rows per workgroup (4 waves x 32 rows)
#define LN2F 0.69314718055994530942f
// SCALEF = sqrt(log2(e)/T) with T=0.5 -> sqrt(2.8853900817779268)
#define SCALEF 1.6986436f

typedef __attribute__((ext_vector_type(8))) short bf8_t;   // 8 bf16 = 4 VGPR
typedef __attribute__((ext_vector_type(4))) float f4_t;    // MFMA C/D frag

__device__ __forceinline__ float fexp2(float x) { return __builtin_amdgcn_exp2f(x); }
__device__ __forceinline__ float flog2(float x) { return __builtin_amdgcn_logf(x); }

__device__ __forceinline__ unsigned short f2bf(float f) {
  unsigned int x = __float_as_uint(f);
  x += 0x7fffu + ((x >> 16) & 1u);   // RNE (no NaN inputs here)
  return (unsigned short)(x >> 16);
}
__device__ __forceinline__ float bf2f(unsigned short h) {
  return __uint_as_float(((unsigned int)h) << 16);
}

// ---------------------------------------------------------------------------
// Kernel 1: normalize rows, scale by sqrt(log2e/T), store bf16 u[8192][128];
// also store dhat[i] = sum_k u_bf16[i][k]^2 (diag logit, for correction).
// ---------------------------------------------------------------------------
__global__ __launch_bounds__(256) void knorm(const float* __restrict__ zi,
                                             const float* __restrict__ zj,
                                             unsigned short* __restrict__ u,
                                             float* __restrict__ dhat) {
  const int lane = threadIdx.x & 63;
  const int row = blockIdx.x * 4 + (threadIdx.x >> 6);
  const float* src = (row < NHALF) ? (zi + (size_t)row * DDIM)
                                   : (zj + (size_t)(row - NHALF) * DDIM);
  float2 x = *(const float2*)(src + lane * 2);
  float ss = x.x * x.x + x.y * x.y;
#pragma unroll
  for (int m = 32; m; m >>= 1) ss += __shfl_xor(ss, m);
  float scale = SCALEF / fmaxf(sqrtf(ss), 1e-8f);  // eps clamp as in reference
  unsigned short b0 = f2bf(x.x * scale);
  unsigned short b1 = f2bf(x.y * scale);
  *(unsigned int*)(u + (size_t)row * DDIM + lane * 2) =
      (unsigned int)b0 | ((unsigned int)b1 << 16);
  float f0 = bf2f(b0), f1 = bf2f(b1);
  float dd = f0 * f0 + f1 * f1;
#pragma unroll
  for (int m = 32; m; m >>= 1) dd += __shfl_xor(dd, m);
  if (lane == 0) dhat[row] = dd;
}

// ---------------------------------------------------------------------------
// Kernel 2: fused sim GEMM + per-row sum of exp2 (logits bounded, no max).
// r3-r9 synthesis: the ONLY spill-free register plan is r3's (VGPR=56
// measured: a[2][4]=32 + L=8 + b=16). Every bigger plan was rematerialized
// (r4) or scratch-spilled (r7/r8), and forcing occupancy via
// launch_bounds(256,8) capped VGPR at 32 and spilled too (r9, WRITE=104MB).
// This round: r3's kernel EXACTLY (plain launch_bounds(256), no caps), with
// occupancy raised purely by grid: NCHUNK=32 -> 2048 WGs = 8 WG/CU =
// 32 waves/CU. VGPR=56 naturally supports 8 waves/SIMD; latency hidden by
// TLP. 4 lockstep waves/WG re-read the same B frags -> L1 broadcast.
// D-frag layout (validated r3+): col = lane&15, row = (lane>>4)*4 + reg.
// ---------------------------------------------------------------------------
__global__ __launch_bounds__(256) void ksim(const unsigned short* __restrict__ u,
                                            float* __restrict__ Lp) {
  const int lane = threadIdx.x & 63;
  const int w = threadIdx.x >> 6;
  const int rb = blockIdx.x >> 5;        // / NCHUNK
  const int chunk = blockIdx.x & (NCHUNK - 1);
  const int lr = lane & 15, lq = lane >> 4;
  const int rowbase = rb * RPB + w * 32;

  bf8_t a[2][4];
#pragma unroll
  for (int s = 0; s < 2; s++)
#pragma unroll
    for (int kc = 0; kc < 4; kc++)
      a[s][kc] = *(const bf8_t*)(u + (size_t)(rowbase + s * 16 + lr) * DDIM +
                                 kc * 32 + lq * 8);

  f4_t L0 = {0.f, 0.f, 0.f, 0.f}, L1 = {0.f, 0.f, 0.f, 0.f};
  const unsigned short* ub = u + (size_t)(chunk * CPC + lr) * DDIM + lq * 8;

  for (int t = 0; t < CPC / 16; t++) {
    bf8_t b[4];
#pragma unroll
    for (int kc = 0; kc < 4; kc++)
      b[kc] = *(const bf8_t*)(ub + (size_t)t * 16 * DDIM + kc * 32);
    f4_t acc0 = {0.f, 0.f, 0.f, 0.f}, acc1 = {0.f, 0.f, 0.f, 0.f};
#pragma unroll
    for (int kc = 0; kc < 4; kc++) {
      acc0 = __builtin_amdgcn_mfma_f32_16x16x32_bf16(a[0][kc], b[kc], acc0, 0, 0, 0);
      acc1 = __builtin_amdgcn_mfma_f32_16x16x32_bf16(a[1][kc], b[kc], acc1, 0, 0, 0);
    }
#pragma unroll
    for (int r = 0; r < 4; r++) {
      L0[r] += fexp2(acc0[r]);
      L1[r] += fexp2(acc1[r]);
    }
  }

  // reduce across the 16 column-lanes (lanes sharing lq hold the same rows)
#pragma unroll
  for (int r = 0; r < 4; r++) {
    float v0 = L0[r], v1 = L1[r];
    v0 += __shfl_xor(v0, 1); v0 += __shfl_xor(v0, 2);
    v0 += __shfl_xor(v0, 4); v0 += __shfl_xor(v0, 8);
    v1 += __shfl_xor(v1, 1); v1 += __shfl_xor(v1, 2);
    v1 += __shfl_xor(v1, 4); v1 += __shfl_xor(v1, 8);
    if (lr == 0) {
      int rrow = rowbase + lq * 4 + r;
      Lp[(size_t)chunk * N2 + rrow] = v0;        // A-set 0 rows
      Lp[(size_t)chunk * N2 + rrow + 16] = v1;   // A-set 1 rows
    }
  }
}

// ---------------------------------------------------------------------------
// Kernel 3: per-row loss. L_i = sum_chunks - exp2(dhat_i) (removes diagonal);
// target logit from direct bf16 dot; loss_i = ln2*(log2(L_i) - target).
// ---------------------------------------------------------------------------
__global__ __launch_bounds__(256) void krow(const unsigned short* __restrict__ u,
                                            const float* __restrict__ dhat,
                                            const float* __restrict__ Lp,
                                            float* __restrict__ bsum) {
  const int i = blockIdx.x * 256 + threadIdx.x;
  float L = 0.f;
#pragma unroll
  for (int c = 0; c < NCHUNK; c++) L += Lp[(size_t)c * N2 + i];
  L -= fexp2(dhat[i]);   // remove self-similarity term (== diag set to -inf)

  const int j = (i + NHALF) & (N2 - 1);  // positive-pair label
  const unsigned int* ui = (const unsigned int*)(u + (size_t)i * DDIM);
  const unsigned int* uj = (const unsigned int*)(u + (size_t)j * DDIM);
  float dot = 0.f;
#pragma unroll
  for (int k = 0; k < DDIM / 2; k++) {
    unsigned int av = ui[k], bv = uj[k];
    dot += __uint_as_float(av << 16) * __uint_as_float(bv << 16) +
           __uint_as_float(av & 0xffff0000u) * __uint_as_float(bv & 0xffff0000u);
  }
  float loss = LN2F * (flog2(L) - dot);

#pragma unroll
  for (int m = 32; m; m >>= 1) loss += __shfl_xor(loss, m);
  __shared__ float sred[4];
  if ((threadIdx.x & 63) == 0) sred[threadIdx.x >> 6] = loss;
  __syncthreads();
  if (threadIdx.x == 0) bsum[blockIdx.x] = sred[0] + sred[1] + sred[2] + sred[3];
}

// ---------------------------------------------------------------------------
// Kernel 4: final mean over the 32 block partials.
// ---------------------------------------------------------------------------
__global__ void kfinal(const float* __restrict__ bsum, float* __restrict__ out) {
  float v = (threadIdx.x < N2 / 256) ? bsum[threadIdx.x] : 0.f;
#pragma unroll
  for (int m = 32; m; m >>= 1) v += __shfl_xor(v, m);
  if (threadIdx.x == 0) out[0] = v * (1.0f / N2);
}

// ---------------------------------------------------------------------------
// ws layout: u bf16 [8192][128] (2 MB) | dhat f32[8192] (32 KB) |
//            Lp f32[NCHUNK][8192] (1 MB) | bsum f32[32]  -> ~3.03 MB total
// ---------------------------------------------------------------------------
extern "C" void kernel_launch(void* const* d_in, const int* in_sizes, int n_in,
                              void* d_out, int out_size, void* d_ws, size_t ws_size,
                              hipStream_t stream) {
  const float* zi = (const float*)d_in[0];
  const float* zj = (const float*)d_in[1];
  char* ws = (char*)d_ws;
  unsigned short* u = (unsigned short*)ws;
  float* dhat = (float*)(ws + (size_t)N2 * DDIM * 2);
  float* Lp = (float*)(ws + (size_t)N2 * DDIM * 2 + (size_t)N2 * 4);
  float* bsum = (float*)(ws + (size_t)N2 * DDIM * 2 + (size_t)N2 * 4 +
                         (size_t)NCHUNK * N2 * 4);
  float* out = (float*)d_out;

  hipLaunchKernelGGL(knorm, dim3(N2 / 4), dim3(256), 0, stream, zi, zj, u, dhat);
  hipLaunchKernelGGL(ksim, dim3((N2 / RPB) * NCHUNK), dim3(256), 0, stream, u, Lp);
  hipLaunchKernelGGL(krow, dim3(N2 / 256), dim3(256), 0, stream, u, dhat, Lp, bsum);
  hipLaunchKernelGGL(kfinal, dim3(1), dim3(64), 0, stream, bsum, out);
}

// Round 11
// 51.389 us; speedup vs baseline: 2.8963x; 1.6249x over previous
//
#include <hip/hip_runtime.h>

#define N2 8192
#define NHALF 4096
#define DDIM 128
#define NCHUNK 16
#define CPC (N2/NCHUNK)   // 512 cols per chunk
#define NT (CPC/64)       // 8 B-tiles of 64 cols
#define RPB 128           // rows per WG (4 waves x 32 rows)
#define LN2F 0.69314718055994530942f
// SCALEF = sqrt(log2(e)/T) with T=0.5 -> sqrt(2.8853900817779268)
#define SCALEF 1.6986436f

typedef __attribute__((ext_vector_type(8))) short bf8_t;   // 8 bf16 = 4 VGPR
typedef __attribute__((ext_vector_type(4))) float f4_t;    // MFMA C/D frag

__device__ __forceinline__ float fexp2(float x) { return __builtin_amdgcn_exp2f(x); }
__device__ __forceinline__ float flog2(float x) { return __builtin_amdgcn_logf(x); }

__device__ __forceinline__ unsigned short f2bf(float f) {
  unsigned int x = __float_as_uint(f);
  x += 0x7fffu + ((x >> 16) & 1u);   // RNE (no NaN inputs here)
  return (unsigned short)(x >> 16);
}
__device__ __forceinline__ float bf2f(unsigned short h) {
  return __uint_as_float(((unsigned int)h) << 16);
}

// ---------------------------------------------------------------------------
// Kernel 1: normalize rows, scale by sqrt(log2e/T), store bf16 u[8192][128];
// also store dhat[i] = sum_k u_bf16[i][k]^2 (diag logit, for correction).
// ---------------------------------------------------------------------------
__global__ __launch_bounds__(256) void knorm(const float* __restrict__ zi,
                                             const float* __restrict__ zj,
                                             unsigned short* __restrict__ u,
                                             float* __restrict__ dhat) {
  const int lane = threadIdx.x & 63;
  const int row = blockIdx.x * 4 + (threadIdx.x >> 6);
  const float* src = (row < NHALF) ? (zi + (size_t)row * DDIM)
                                   : (zj + (size_t)(row - NHALF) * DDIM);
  float2 x = *(const float2*)(src + lane * 2);
  float ss = x.x * x.x + x.y * x.y;
#pragma unroll
  for (int m = 32; m; m >>= 1) ss += __shfl_xor(ss, m);
  float scale = SCALEF / fmaxf(sqrtf(ss), 1e-8f);  // eps clamp as in reference
  unsigned short b0 = f2bf(x.x * scale);
  unsigned short b1 = f2bf(x.y * scale);
  *(unsigned int*)(u + (size_t)row * DDIM + lane * 2) =
      (unsigned int)b0 | ((unsigned int)b1 << 16);
  float f0 = bf2f(b0), f1 = bf2f(b1);
  float dd = f0 * f0 + f1 * f1;
#pragma unroll
  for (int m = 32; m; m >>= 1) dd += __shfl_xor(dd, m);
  if (lane == 0) dhat[row] = dd;
}

// ---------------------------------------------------------------------------
// Kernel 2: fused sim GEMM + per-row sum of exp2 (logits bounded, no max).
// r10 post-mortem: the per-CU limiter is the gathered B-load (16x64B
// segments/instr); occupancy didn't help. Fix: B-tile (64 consecutive u-rows
// = CONTIGUOUS 16KB) staged via global_load_lds, source lane-contiguous
// 1KB/instr. LDS dest linear (HW requirement); layout permutation applied on
// the per-lane SOURCE address inside each 1KB region (rule #21 / m173):
//   LDS 16B-unit U holds global unit (U&~15) | ((U&15) ^ ((U>>4)&7)).
// Fragment read (colgroup g, kc), lane l (lr=l&15,lq=l>>4):
//   unit = (g*16+lr)*16 + ((kc*4+lq)^(lr&7))
// -> 8 lanes per 4-bank group, even spread = conflict-free b128.
// Sync: counted s_waitcnt vmcnt(4) + raw s_barrier (r7-proven), no full
// drain in-loop. Registers kept small (a[2][4]=32, acc 8, L 8): no
// launch_bounds cap (r9 lesson), A pinned once (r5-proven).
// grid = 64 row-blocks x 16 chunks = 1024 WGs; LDS 32KB -> 4 WGs/CU resident.
// ---------------------------------------------------------------------------
__global__ __launch_bounds__(256) void ksim(const unsigned short* __restrict__ u,
                                            float* __restrict__ Lp) {
  __shared__ short Bl[2][8192];  // 2 x 16 KB
  const int tid = threadIdx.x;
  const int lane = tid & 63;
  const int w = tid >> 6;
  const int rb = blockIdx.x >> 4;        // / NCHUNK
  const int chunk = blockIdx.x & (NCHUNK - 1);
  const int lr = lane & 15, lq = lane >> 4;
  const int rowbase = rb * RPB + w * 32;

  // A fragments: 32 rows per wave, loaded once from global, pinned.
  bf8_t a[2][4];
#pragma unroll
  for (int s = 0; s < 2; s++)
#pragma unroll
    for (int kc = 0; kc < 4; kc++)
      a[s][kc] = *(const bf8_t*)(u + (size_t)(rowbase + s * 16 + lr) * DDIM +
                                 kc * 32 + lq * 8);
#pragma unroll
  for (int s = 0; s < 2; s++)
#pragma unroll
    for (int kc = 0; kc < 4; kc++)
      asm volatile("" : "+v"(a[s][kc]));

  f4_t L0 = {0.f, 0.f, 0.f, 0.f}, L1 = {0.f, 0.f, 0.f, 0.f};

  // Staging source (per-lane, swizzled within each 1KB region):
  // dest unit U = i*256 + tid; col = U>>4, d = (U&15) ^ ((U>>4)&7)
  const int scol = tid >> 4;                       // 0..15 (instr i adds i*16)
  const int sd = (tid & 15) ^ (scol & 7);          // (i*16)&7 == 0
  const unsigned short* sbase =
      u + (size_t)chunk * CPC * DDIM + (size_t)scol * DDIM + sd * 8;

  auto STAGE = [&](int t, int bufi) {
#pragma unroll
    for (int i = 0; i < 4; i++) {
      const unsigned short* src = sbase + (size_t)t * 64 * DDIM + i * 16 * DDIM;
      short* dst = &Bl[bufi][(i * 256 + w * 64) * 8];   // wave-uniform, linear
      __builtin_amdgcn_global_load_lds(
          (const __attribute__((address_space(1))) unsigned int*)src,
          (__attribute__((address_space(3))) unsigned int*)dst, 16, 0, 0);
    }
  };

  auto COMP = [&](int bufi) {
    const short* bb = &Bl[bufi][0];
#pragma unroll
    for (int g = 0; g < 4; g++) {
      f4_t acc0 = {0.f, 0.f, 0.f, 0.f}, acc1 = {0.f, 0.f, 0.f, 0.f};
#pragma unroll
      for (int kc = 0; kc < 4; kc++) {
        bf8_t bv = *(const bf8_t*)&bb[(((g * 16 + lr) * 16) +
                                       ((kc * 4 + lq) ^ (lr & 7))) * 8];
        acc0 = __builtin_amdgcn_mfma_f32_16x16x32_bf16(a[0][kc], bv, acc0, 0, 0, 0);
        acc1 = __builtin_amdgcn_mfma_f32_16x16x32_bf16(a[1][kc], bv, acc1, 0, 0, 0);
      }
#pragma unroll
      for (int r = 0; r < 4; r++) {
        L0[r] += fexp2(acc0[r]);
        L1[r] += fexp2(acc1[r]);
      }
    }
  };

  STAGE(0, 0);
#pragma unroll
  for (int t = 0; t < NT - 1; t++) {
    STAGE(t + 1, (t + 1) & 1);
    asm volatile("s_waitcnt vmcnt(4)" ::: "memory");  // my tile-t DMAs done
    __builtin_amdgcn_sched_barrier(0);
    __builtin_amdgcn_s_barrier();                     // everyone's tile-t done
    __builtin_amdgcn_sched_barrier(0);
    COMP(t & 1);
    __builtin_amdgcn_s_barrier();                     // all done reading buf
    __builtin_amdgcn_sched_barrier(0);
  }
  asm volatile("s_waitcnt vmcnt(0)" ::: "memory");
  __builtin_amdgcn_sched_barrier(0);
  __builtin_amdgcn_s_barrier();
  __builtin_amdgcn_sched_barrier(0);
  COMP((NT - 1) & 1);

  // reduce across the 16 column-lanes (lanes sharing lq hold the same rows)
#pragma unroll
  for (int r = 0; r < 4; r++) {
    float v0 = L0[r], v1 = L1[r];
    v0 += __shfl_xor(v0, 1); v0 += __shfl_xor(v0, 2);
    v0 += __shfl_xor(v0, 4); v0 += __shfl_xor(v0, 8);
    v1 += __shfl_xor(v1, 1); v1 += __shfl_xor(v1, 2);
    v1 += __shfl_xor(v1, 4); v1 += __shfl_xor(v1, 8);
    if (lr == 0) {
      int rrow = rowbase + lq * 4 + r;
      Lp[(size_t)chunk * N2 + rrow] = v0;        // A-set 0 rows
      Lp[(size_t)chunk * N2 + rrow + 16] = v1;   // A-set 1 rows
    }
  }
}

// ---------------------------------------------------------------------------
// Kernel 3: per-row loss. L_i = sum_chunks - exp2(dhat_i) (removes diagonal);
// target logit from direct bf16 dot; loss_i = ln2*(log2(L_i) - target).
// ---------------------------------------------------------------------------
__global__ __launch_bounds__(256) void krow(const unsigned short* __restrict__ u,
                                            const float* __restrict__ dhat,
                                            const float* __restrict__ Lp,
                                            float* __restrict__ bsum) {
  const int i = blockIdx.x * 256 + threadIdx.x;
  float L = 0.f;
#pragma unroll
  for (int c = 0; c < NCHUNK; c++) L += Lp[(size_t)c * N2 + i];
  L -= fexp2(dhat[i]);   // remove self-similarity term (== diag set to -inf)

  const int j = (i + NHALF) & (N2 - 1);  // positive-pair label
  const unsigned int* ui = (const unsigned int*)(u + (size_t)i * DDIM);
  const unsigned int* uj = (const unsigned int*)(u + (size_t)j * DDIM);
  float dot = 0.f;
#pragma unroll
  for (int k = 0; k < DDIM / 2; k++) {
    unsigned int av = ui[k], bv = uj[k];
    dot += __uint_as_float(av << 16) * __uint_as_float(bv << 16) +
           __uint_as_float(av & 0xffff0000u) * __uint_as_float(bv & 0xffff0000u);
  }
  float loss = LN2F * (flog2(L) - dot);

#pragma unroll
  for (int m = 32; m; m >>= 1) loss += __shfl_xor(loss, m);
  __shared__ float sred[4];
  if ((threadIdx.x & 63) == 0) sred[threadIdx.x >> 6] = loss;
  __syncthreads();
  if (threadIdx.x == 0) bsum[blockIdx.x] = sred[0] + sred[1] + sred[2] + sred[3];
}

// ---------------------------------------------------------------------------
// Kernel 4: final mean over the 32 block partials.
// ---------------------------------------------------------------------------
__global__ void kfinal(const float* __restrict__ bsum, float* __restrict__ out) {
  float v = (threadIdx.x < N2 / 256) ? bsum[threadIdx.x] : 0.f;
#pragma unroll
  for (int m = 32; m; m >>= 1) v += __shfl_xor(v, m);
  if (threadIdx.x == 0) out[0] = v * (1.0f / N2);
}

// ---------------------------------------------------------------------------
// ws layout: u bf16 [8192][128] (2 MB) | dhat f32[8192] (32 KB) |
//            Lp f32[NCHUNK][8192] (512 KB) | bsum f32[32]  -> ~2.6 MB total
// ---------------------------------------------------------------------------
extern "C" void kernel_launch(void* const* d_in, const int* in_sizes, int n_in,
                              void* d_out, int out_size, void* d_ws, size_t ws_size,
                              hipStream_t stream) {
  const float* zi = (const float*)d_in[0];
  const float* zj = (const float*)d_in[1];
  char* ws = (char*)d_ws;
  unsigned short* u = (unsigned short*)ws;
  float* dhat = (float*)(ws + (size_t)N2 * DDIM * 2);
  float* Lp = (float*)(ws + (size_t)N2 * DDIM * 2 + (size_t)N2 * 4);
  float* bsum = (float*)(ws + (size_t)N2 * DDIM * 2 + (size_t)N2 * 4 +
                         (size_t)NCHUNK * N2 * 4);
  float* out = (float*)d_out;

  hipLaunchKernelGGL(knorm, dim3(N2 / 4), dim3(256), 0, stream, zi, zj, u, dhat);
  hipLaunchKernelGGL(ksim, dim3((N2 / RPB) * NCHUNK), dim3(256), 0, stream, u, Lp);
  hipLaunchKernelGGL(krow, dim3(N2 / 256), dim3(256), 0, stream, u, dhat, Lp, bsum);
  hipLaunchKernelGGL(kfinal, dim3(1), dim3(64), 0, stream, bsum, out);
}

// Round 12
// 47.882 us; speedup vs baseline: 3.1085x; 1.0732x over previous
//
#include <hip/hip_runtime.h>

#define N2 8192
#define NHALF 4096
#define DDIM 128
#define NPART 64          // Lp partials per row (16 chunks x 4 waves)
#define LN2F 0.69314718055994530942f
// SCALEF = sqrt(log2(e)/T) with T=0.5 -> sqrt(2.8853900817779268)
#define SCALEF 1.6986436f

typedef __attribute__((ext_vector_type(8))) short bf8_t;   // 8 bf16 = 4 VGPR
typedef __attribute__((ext_vector_type(4))) float f4_t;    // MFMA C/D frag

__device__ __forceinline__ float fexp2(float x) { return __builtin_amdgcn_exp2f(x); }
__device__ __forceinline__ float flog2(float x) { return __builtin_amdgcn_logf(x); }

__device__ __forceinline__ unsigned short f2bf(float f) {
  unsigned int x = __float_as_uint(f);
  x += 0x7fffu + ((x >> 16) & 1u);   // RNE (no NaN inputs here)
  return (unsigned short)(x >> 16);
}
__device__ __forceinline__ float bf2f(unsigned short h) {
  return __uint_as_float(((unsigned int)h) << 16);
}

// ---------------------------------------------------------------------------
// Kernel 1: normalize rows, scale by sqrt(log2e/T), store bf16 u[8192][128];
// also store dhat[i] = sum_k u_bf16[i][k]^2 (diag logit). Unchanged (passing).
// ---------------------------------------------------------------------------
__global__ __launch_bounds__(256) void knorm(const float* __restrict__ zi,
                                             const float* __restrict__ zj,
                                             unsigned short* __restrict__ u,
                                             float* __restrict__ dhat) {
  const int lane = threadIdx.x & 63;
  const int row = blockIdx.x * 4 + (threadIdx.x >> 6);
  const float* src = (row < NHALF) ? (zi + (size_t)row * DDIM)
                                   : (zj + (size_t)(row - NHALF) * DDIM);
  float2 x = *(const float2*)(src + lane * 2);
  float ss = x.x * x.x + x.y * x.y;
#pragma unroll
  for (int m = 32; m; m >>= 1) ss += __shfl_xor(ss, m);
  float scale = SCALEF / fmaxf(sqrtf(ss), 1e-8f);  // eps clamp as in reference
  unsigned short b0 = f2bf(x.x * scale);
  unsigned short b1 = f2bf(x.y * scale);
  *(unsigned int*)(u + (size_t)row * DDIM + lane * 2) =
      (unsigned int)b0 | ((unsigned int)b1 << 16);
  float f0 = bf2f(b0), f1 = bf2f(b1);
  float dd = f0 * f0 + f1 * f1;
#pragma unroll
  for (int m = 32; m; m >>= 1) dd += __shfl_xor(dd, m);
  if (lane == 0) dhat[row] = dd;
}

// ---------------------------------------------------------------------------
// Kernel 2: fused sim GEMM + per-row sum of exp2 (logits bounded, no max).
// r11 post-mortem: linear DMA+LDS fixed the memory system (FETCH 8MB) but
// the 2-barrier-per-tile lockstep at 3 WGs/CU serialized everything
// (occupancy 9%, both pipes <25%). This round: ZERO barriers in steady state.
// WG = 64 rows x 512 cols; each wave owns a PRIVATE 128-col strip + private
// 8KB LDS double-buffer; per-wave pipeline synced only by its own counted
// vmcnt(4) (DMA -> own-wave LDS visibility). A (the WG's 64 contiguous rows
// = 16KB linear) is DMA-staged once, frag-extracted (XOR-swizzle), pinned in
// regs; 2 barriers total per WG, then the A region is recycled as B space.
// Swizzle (both-sides involution, validated r11): 16B-unit d stored at
// d^(col&7) within each col's 256B row; reads apply the same XOR -> ~2-way.
// grid = 128 row-blocks x 16 chunks = 2048 WGs; LDS 32KB.
// ---------------------------------------------------------------------------
__global__ __launch_bounds__(256) void ksim(const unsigned short* __restrict__ u,
                                            float* __restrict__ Lp) {
  __shared__ short Bls[16384];  // 32KB: A-stage first 16KB, then 4x8KB B dbuf
  const int tid = threadIdx.x;
  const int lane = tid & 63;
  const int w = tid >> 6;
  const int rb = blockIdx.x >> 4;          // 0..127
  const int chunk = blockIdx.x & 15;       // 0..15
  const int lr = lane & 15, lq = lane >> 4;
  const int rowbase = rb * 64;
  const int colbase = chunk * 512 + w * 128;   // wave's private col strip

  // ---- A stage: 64 rows = 16KB contiguous, 16 linear DMAs (4 per wave),
  // source pre-swizzled within each 256B row: unit d stored at d^(row&7).
#pragma unroll
  for (int i = 0; i < 4; i++) {
    const int j = w * 4 + i;                       // 1KB block index 0..15
    const int row_local = j * 4 + (lane >> 4);     // 4 rows per block
    const int sdu = (lane & 15) ^ (row_local & 7);
    const unsigned short* src =
        u + (size_t)(rowbase + row_local) * DDIM + sdu * 8;
    short* dst = &Bls[j * 512];                    // wave-uniform, linear
    __builtin_amdgcn_global_load_lds(
        (const __attribute__((address_space(1))) unsigned int*)src,
        (__attribute__((address_space(3))) unsigned int*)dst, 16, 0, 0);
  }
  asm volatile("s_waitcnt vmcnt(0)" ::: "memory");
  __builtin_amdgcn_sched_barrier(0);
  __builtin_amdgcn_s_barrier();                    // A staged (all waves)

  // ---- A frag extract (swizzled read), then pin in VGPRs.
  bf8_t a[4][4];
#pragma unroll
  for (int s = 0; s < 4; s++)
#pragma unroll
    for (int kc = 0; kc < 4; kc++)
      a[s][kc] = *(const bf8_t*)&Bls[(s * 16 + lr) * 128 +
                                     ((kc * 32 + lq * 8) ^ ((lr & 7) << 3))];
#pragma unroll
  for (int s = 0; s < 4; s++)
#pragma unroll
    for (int kc = 0; kc < 4; kc++)
      asm volatile("" : "+v"(a[s][kc]));           // forces lgkm drain too
  __builtin_amdgcn_s_barrier();                    // all A-reads done
  // ---- from here: NO barriers; per-wave private streaming.

  short* const Pbase = &Bls[w * 4096];             // wave's 8KB double-buffer

  auto STAGE = [&](int t) {                        // 16 cols -> 4 linear DMAs
#pragma unroll
    for (int i = 0; i < 4; i++) {
      const int colg = t * 16 + i * 4 + (lane >> 4);   // col within strip
      const int sdu = (lane & 15) ^ (colg & 7);        // colbase%128==0
      const unsigned short* src =
          u + (size_t)(colbase + colg) * DDIM + sdu * 8;
      short* dst = Pbase + (t & 1) * 2048 + i * 512;   // wave-uniform
      __builtin_amdgcn_global_load_lds(
          (const __attribute__((address_space(1))) unsigned int*)src,
          (__attribute__((address_space(3))) unsigned int*)dst, 16, 0, 0);
    }
  };

  f4_t L[4];
#pragma unroll
  for (int s = 0; s < 4; s++) L[s] = (f4_t){0.f, 0.f, 0.f, 0.f};

  auto COMP = [&](int t) {
    const short* P = Pbase + (t & 1) * 2048;
    bf8_t bv[4];
#pragma unroll
    for (int kc = 0; kc < 4; kc++)
      bv[kc] = *(const bf8_t*)&P[lr * 128 + (((kc * 4 + lq) ^ (lr & 7)) * 8)];
    f4_t acc[4];
#pragma unroll
    for (int s = 0; s < 4; s++) acc[s] = (f4_t){0.f, 0.f, 0.f, 0.f};
#pragma unroll
    for (int kc = 0; kc < 4; kc++)
#pragma unroll
      for (int s = 0; s < 4; s++)
        acc[s] = __builtin_amdgcn_mfma_f32_16x16x32_bf16(a[s][kc], bv[kc], acc[s], 0, 0, 0);
#pragma unroll
    for (int s = 0; s < 4; s++)
#pragma unroll
      for (int r = 0; r < 4; r++) L[s][r] += fexp2(acc[s][r]);
  };

  // per-wave pipeline over 8 tiles, 2 in flight, counted vmcnt only
  STAGE(0);
  STAGE(1);
  for (int tp = 0; tp < 3; tp++) {
    asm volatile("s_waitcnt vmcnt(4)" ::: "memory");   // tile 2tp ready
    __builtin_amdgcn_sched_barrier(0);
    COMP(2 * tp);
    STAGE(2 * tp + 2);
    asm volatile("s_waitcnt vmcnt(4)" ::: "memory");   // tile 2tp+1 ready
    __builtin_amdgcn_sched_barrier(0);
    COMP(2 * tp + 1);
    STAGE(2 * tp + 3);
  }
  asm volatile("s_waitcnt vmcnt(4)" ::: "memory");
  __builtin_amdgcn_sched_barrier(0);
  COMP(6);
  asm volatile("s_waitcnt vmcnt(0)" ::: "memory");
  __builtin_amdgcn_sched_barrier(0);
  COMP(7);

  // reduce across the 16 column-lanes; partial p = chunk*4 + w
  const int p = chunk * 4 + w;
#pragma unroll
  for (int s = 0; s < 4; s++)
#pragma unroll
    for (int r = 0; r < 4; r++) {
      float v = L[s][r];
      v += __shfl_xor(v, 1); v += __shfl_xor(v, 2);
      v += __shfl_xor(v, 4); v += __shfl_xor(v, 8);
      if (lr == 0)
        Lp[(size_t)p * N2 + rowbase + s * 16 + lq * 4 + r] = v;
    }
}

// ---------------------------------------------------------------------------
// Kernel 3: per-row loss. L_i = sum of 64 partials - exp2(dhat_i);
// target logit from direct bf16 dot; loss_i = ln2*(log2(L_i) - target).
// ---------------------------------------------------------------------------
__global__ __launch_bounds__(256) void krow(const unsigned short* __restrict__ u,
                                            const float* __restrict__ dhat,
                                            const float* __restrict__ Lp,
                                            float* __restrict__ bsum) {
  const int i = blockIdx.x * 256 + threadIdx.x;
  float L = 0.f;
#pragma unroll
  for (int c = 0; c < NPART; c++) L += Lp[(size_t)c * N2 + i];
  L -= fexp2(dhat[i]);   // remove self-similarity term (== diag set to -inf)

  const int j = (i + NHALF) & (N2 - 1);  // positive-pair label
  const unsigned int* ui = (const unsigned int*)(u + (size_t)i * DDIM);
  const unsigned int* uj = (const unsigned int*)(u + (size_t)j * DDIM);
  float dot = 0.f;
#pragma unroll
  for (int k = 0; k < DDIM / 2; k++) {
    unsigned int av = ui[k], bv = uj[k];
    dot += __uint_as_float(av << 16) * __uint_as_float(bv << 16) +
           __uint_as_float(av & 0xffff0000u) * __uint_as_float(bv & 0xffff0000u);
  }
  float loss = LN2F * (flog2(L) - dot);

#pragma unroll
  for (int m = 32; m; m >>= 1) loss += __shfl_xor(loss, m);
  __shared__ float sred[4];
  if ((threadIdx.x & 63) == 0) sred[threadIdx.x >> 6] = loss;
  __syncthreads();
  if (threadIdx.x == 0) bsum[blockIdx.x] = sred[0] + sred[1] + sred[2] + sred[3];
}

// ---------------------------------------------------------------------------
// Kernel 4: final mean over the 32 block partials.
// ---------------------------------------------------------------------------
__global__ void kfinal(const float* __restrict__ bsum, float* __restrict__ out) {
  float v = (threadIdx.x < N2 / 256) ? bsum[threadIdx.x] : 0.f;
#pragma unroll
  for (int m = 32; m; m >>= 1) v += __shfl_xor(v, m);
  if (threadIdx.x == 0) out[0] = v * (1.0f / N2);
}

// ---------------------------------------------------------------------------
// ws layout: u bf16 [8192][128] (2 MB) | dhat f32[8192] (32 KB) |
//            Lp f32[NPART][8192] (2 MB) | bsum f32[32]  -> ~4.03 MB total
// ---------------------------------------------------------------------------
extern "C" void kernel_launch(void* const* d_in, const int* in_sizes, int n_in,
                              void* d_out, int out_size, void* d_ws, size_t ws_size,
                              hipStream_t stream) {
  const float* zi = (const float*)d_in[0];
  const float* zj = (const float*)d_in[1];
  char* ws = (char*)d_ws;
  unsigned short* u = (unsigned short*)ws;
  float* dhat = (float*)(ws + (size_t)N2 * DDIM * 2);
  float* Lp = (float*)(ws + (size_t)N2 * DDIM * 2 + (size_t)N2 * 4);
  float* bsum = (float*)(ws + (size_t)N2 * DDIM * 2 + (size_t)N2 * 4 +
                         (size_t)NPART * N2 * 4);
  float* out = (float*)d_out;

  hipLaunchKernelGGL(knorm, dim3(N2 / 4), dim3(256), 0, stream, zi, zj, u, dhat);
  hipLaunchKernelGGL(ksim, dim3((N2 / 64) * 16), dim3(256), 0, stream, u, Lp);
  hipLaunchKernelGGL(krow, dim3(N2 / 256), dim3(256), 0, stream, u, dhat, Lp, bsum);
  hipLaunchKernelGGL(kfinal, dim3(1), dim3(64), 0, stream, bsum, out);
}